// Round 2
// baseline (1003.541 us; speedup 1.0000x reference)
//
#include <hip/hip_runtime.h>
#include <cstddef>

#define B0V 8
#define HSV 96
#define WSV 96
#define DMV 192
#define DIV 384
#define MTOT (B0V*HSV*WSV)   // 73728

typedef __attribute__((ext_vector_type(8))) unsigned short ushort8v;

__device__ __forceinline__ float bf2f(unsigned short u) {
    unsigned int i = ((unsigned int)u) << 16;
    float f; __builtin_memcpy(&f, &i, 4); return f;
}
__device__ __forceinline__ unsigned short f2bf(float f) {
    unsigned int i; __builtin_memcpy(&i, &f, 4);
    i += 0x7FFFu + ((i >> 16) & 1);
    return (unsigned short)(i >> 16);
}

// ---------------- K0: Wc(192x192) = W_out(192x384) @ W_in_z(384x192) ----------------
__global__ __launch_bounds__(192) void wc_kernel(
    const float* __restrict__ Wout, const float* __restrict__ Win, float* __restrict__ Wc)
{
    const int o = blockIdx.x;     // 0..191
    const int c = threadIdx.x;    // 0..191
    __shared__ float wrow[384];
    for (int j = threadIdx.x; j < 384; j += 192) wrow[j] = Wout[(size_t)o*384 + j];
    __syncthreads();
    float acc = 0.f;
#pragma unroll 4
    for (int j = 0; j < 384; ++j)
        acc += wrow[j] * Win[(size_t)(384 + j)*192 + c];
    Wc[(size_t)o*192 + c] = acc;
}

// ---------------- K1: xf(bf16) = x(M x 192) @ W_in_f^T(384 x 192) ----------------
__global__ __launch_bounds__(256) void gemm_in_kernel(
    const float* __restrict__ A, const float* __restrict__ Bm,
    unsigned short* __restrict__ xf)
{
    const int m0 = blockIdx.x * 128;
    const int n0 = blockIdx.y * 128;
    __shared__ float As[16][132];
    __shared__ float Bs[16][132];
    const int t  = threadIdx.x;
    const int tx = t & 15, ty = t >> 4;
    float acc[8][8];
#pragma unroll
    for (int i = 0; i < 8; ++i)
#pragma unroll
        for (int j = 0; j < 8; ++j) acc[i][j] = 0.f;

    const int row = t >> 1;
    const int kof = (t & 1) * 8;

    for (int k0 = 0; k0 < 192; k0 += 16) {
        const float* srcA = A  + (size_t)(m0 + row) * 192 + k0 + kof;
        float4 a0 = *(const float4*)(srcA);
        float4 a1 = *(const float4*)(srcA + 4);
        const float* srcB = Bm + (size_t)(n0 + row) * 192 + k0 + kof;
        float4 b0 = *(const float4*)(srcB);
        float4 b1 = *(const float4*)(srcB + 4);
        __syncthreads();
        As[kof+0][row]=a0.x; As[kof+1][row]=a0.y; As[kof+2][row]=a0.z; As[kof+3][row]=a0.w;
        As[kof+4][row]=a1.x; As[kof+5][row]=a1.y; As[kof+6][row]=a1.z; As[kof+7][row]=a1.w;
        Bs[kof+0][row]=b0.x; Bs[kof+1][row]=b0.y; Bs[kof+2][row]=b0.z; Bs[kof+3][row]=b0.w;
        Bs[kof+4][row]=b1.x; Bs[kof+5][row]=b1.y; Bs[kof+6][row]=b1.z; Bs[kof+7][row]=b1.w;
        __syncthreads();
#pragma unroll
        for (int kk = 0; kk < 16; ++kk) {
            float a[8], b[8];
            *(float4*)&a[0] = *(const float4*)&As[kk][ty*8];
            *(float4*)&a[4] = *(const float4*)&As[kk][ty*8+4];
            *(float4*)&b[0] = *(const float4*)&Bs[kk][tx*8];
            *(float4*)&b[4] = *(const float4*)&Bs[kk][tx*8+4];
#pragma unroll
            for (int i = 0; i < 8; ++i)
#pragma unroll
                for (int j = 0; j < 8; ++j) acc[i][j] += a[i]*b[j];
        }
    }
    const int ncol = n0 + tx*8;
#pragma unroll
    for (int i = 0; i < 8; ++i) {
        const int m = m0 + ty*8 + i;
        ushort8v sv;
#pragma unroll
        for (int j = 0; j < 8; ++j) sv[j] = f2bf(acc[i][j]);
        *(ushort8v*)(xf + (size_t)m*DIV + ncol) = sv;
    }
}

// ---------------- K2: depthwise 7x7 conv, pad 3, bf16 in/out ----------------
__global__ __launch_bounds__(256) void dwconv_kernel(
    const unsigned short* __restrict__ xf, const float* __restrict__ cw,
    const float* __restrict__ cb, unsigned short* __restrict__ xc)
{
    const int tile = blockIdx.x;          // 0..143 (12x12 tiles of 8x8)
    const int th = tile / 12, tw = tile % 12;
    const int c0 = blockIdx.y * 64;       // channel chunk
    const int b  = blockIdx.z;
    const int h0 = th * 8, w0 = tw * 8;

    __shared__ float patch[196][64];      // 14x14 spatial x 64 channels
    __shared__ float wl[64*49];           // [c_local][tap]

    const int t = threadIdx.x;
    for (int idx = t; idx < 64*49; idx += 256)
        wl[idx] = cw[(size_t)c0*49 + idx];

    const int c   = t & 63;
    const int sp0 = t >> 6;               // 0..3
    for (int sp = sp0; sp < 196; sp += 4) {
        const int ph = sp / 14, pw = sp % 14;
        const int gh = h0 - 3 + ph, gw = w0 - 3 + pw;
        float v = 0.f;
        if (gh >= 0 && gh < HSV && gw >= 0 && gw < WSV)
            v = bf2f(xf[(((size_t)b*HSV + gh)*WSV + gw)*DIV + c0 + c]);
        patch[sp][c] = v;
    }
    __syncthreads();

    float acc[16];
    const float bias = cb[c0 + c];
#pragma unroll
    for (int i = 0; i < 16; ++i) acc[i] = bias;

    for (int tap = 0; tap < 49; ++tap) {
        const float wv = wl[c*49 + tap];
        const int kh = tap / 7, kw = tap % 7;
#pragma unroll
        for (int i = 0; i < 16; ++i) {
            const int s  = sp0 + 4*i;     // 0..63
            const int sh = s >> 3, sw = s & 7;
            acc[i] += patch[(sh+kh)*14 + (sw+kw)][c] * wv;
        }
    }
#pragma unroll
    for (int i = 0; i < 16; ++i) {
        const int s  = sp0 + 4*i;
        const int sh = s >> 3, sw = s & 7;
        xc[(((size_t)b*HSV + h0+sh)*WSV + (w0+sw))*DIV + c0 + c] = f2bf(acc[i]);
    }
}

// ---------------- K3: dilated 3x3 box-sum + LayerNorm ----------------
__global__ __launch_bounds__(384) void boxln_kernel(
    const unsigned short* __restrict__ xc,
    const float* __restrict__ g, const float* __restrict__ bta,
    unsigned short* __restrict__ yln)
{
    const int m = blockIdx.x;            // pixel index
    const int b  = m / (HSV*WSV);
    const int hw = m % (HSV*WSV);
    const int h = hw / WSV, w = hw % WSV;
    const int d = threadIdx.x;           // 0..383
    const int grp = d >> 7;              // d / 128
    const int dd  = grp + 1;             // dilation

    float s = 0.f;
#pragma unroll
    for (int a = -1; a <= 1; ++a)
#pragma unroll
        for (int bb = -1; bb <= 1; ++bb) {
            const int h2 = h + a*dd, w2 = w + bb*dd;
            if (h2 >= 0 && h2 < HSV && w2 >= 0 && w2 < WSV)
                s += bf2f(xc[(((size_t)b*HSV + h2)*WSV + w2)*DIV + d]);
        }

    // LayerNorm over 384 channels
    float v = s, v2 = s*s;
#pragma unroll
    for (int off = 32; off > 0; off >>= 1) {
        v  += __shfl_down(v,  off);
        v2 += __shfl_down(v2, off);
    }
    __shared__ float red[14];
    const int wid = threadIdx.x >> 6, lane = threadIdx.x & 63;
    if (lane == 0) { red[wid] = v; red[6+wid] = v2; }
    __syncthreads();
    if (threadIdx.x == 0) {
        float sv = 0.f, sv2 = 0.f;
        for (int i = 0; i < 6; ++i) { sv += red[i]; sv2 += red[6+i]; }
        const float mu  = sv * (1.f/384.f);
        const float var = sv2 * (1.f/384.f) - mu*mu;
        red[12] = mu;
        red[13] = rsqrtf(var + 1e-5f);
    }
    __syncthreads();
    const float mu = red[12], rstd = red[13];
    yln[(size_t)m*DIV + d] = f2bf((s - mu)*rstd*g[d] + bta[d]);
}

// ---------------- K4: out = yln(bf16, M x 384) @ W_out^T + x @ Wc^T ----------------
__global__ __launch_bounds__(256) void gemm_out_kernel(
    const unsigned short* __restrict__ Yl, const float* __restrict__ Wout,
    const float* __restrict__ x, const float* __restrict__ Wc,
    float* __restrict__ out)
{
    const int m0 = blockIdx.x * 128;
    const int n0 = blockIdx.y * 64;
    __shared__ float As[16][132];
    __shared__ float Bs[16][68];
    const int t  = threadIdx.x;
    const int tx = t & 15, ty = t >> 4;
    float acc[8][4];
#pragma unroll
    for (int i = 0; i < 8; ++i)
#pragma unroll
        for (int j = 0; j < 4; ++j) acc[i][j] = 0.f;

    const int rowA = t >> 1; const int kofA = (t & 1) * 8;
    const int rowB = t >> 2; const int kofB = (t & 3) * 4;

    // phase 1: K=384 over yln (bf16) x W_out (f32)
    for (int k0 = 0; k0 < 384; k0 += 16) {
        ushort8v av = *(const ushort8v*)(Yl + (size_t)(m0 + rowA) * DIV + k0 + kofA);
        float4 b0 = *(const float4*)(Wout + (size_t)(n0 + rowB) * DIV + k0 + kofB);
        __syncthreads();
#pragma unroll
        for (int j = 0; j < 8; ++j) As[kofA+j][rowA] = bf2f(av[j]);
        Bs[kofB+0][rowB]=b0.x; Bs[kofB+1][rowB]=b0.y; Bs[kofB+2][rowB]=b0.z; Bs[kofB+3][rowB]=b0.w;
        __syncthreads();
#pragma unroll
        for (int kk = 0; kk < 16; ++kk) {
            float a[8], b[4];
            *(float4*)&a[0] = *(const float4*)&As[kk][ty*8];
            *(float4*)&a[4] = *(const float4*)&As[kk][ty*8+4];
            *(float4*)&b[0] = *(const float4*)&Bs[kk][tx*4];
#pragma unroll
            for (int i = 0; i < 8; ++i)
#pragma unroll
                for (int j = 0; j < 4; ++j) acc[i][j] += a[i]*b[j];
        }
    }
    // phase 2: K=192 over x (f32) x Wc (f32)
    for (int k0 = 0; k0 < 192; k0 += 16) {
        const float* srcA = x + (size_t)(m0 + rowA) * 192 + k0 + kofA;
        float4 a0 = *(const float4*)(srcA);
        float4 a1 = *(const float4*)(srcA + 4);
        float4 b0 = *(const float4*)(Wc + (size_t)(n0 + rowB) * 192 + k0 + kofB);
        __syncthreads();
        As[kofA+0][rowA]=a0.x; As[kofA+1][rowA]=a0.y; As[kofA+2][rowA]=a0.z; As[kofA+3][rowA]=a0.w;
        As[kofA+4][rowA]=a1.x; As[kofA+5][rowA]=a1.y; As[kofA+6][rowA]=a1.z; As[kofA+7][rowA]=a1.w;
        Bs[kofB+0][rowB]=b0.x; Bs[kofB+1][rowB]=b0.y; Bs[kofB+2][rowB]=b0.z; Bs[kofB+3][rowB]=b0.w;
        __syncthreads();
#pragma unroll
        for (int kk = 0; kk < 16; ++kk) {
            float a[8], b[4];
            *(float4*)&a[0] = *(const float4*)&As[kk][ty*8];
            *(float4*)&a[4] = *(const float4*)&As[kk][ty*8+4];
            *(float4*)&b[0] = *(const float4*)&Bs[kk][tx*4];
#pragma unroll
            for (int i = 0; i < 8; ++i)
#pragma unroll
                for (int j = 0; j < 4; ++j) acc[i][j] += a[i]*b[j];
        }
    }
    const int ncol = n0 + tx*4;
#pragma unroll
    for (int i = 0; i < 8; ++i) {
        const int m = m0 + ty*8 + i;
        float4 s0 = make_float4(acc[i][0],acc[i][1],acc[i][2],acc[i][3]);
        *(float4*)(out + (size_t)m*DMV + ncol) = s0;
    }
}

extern "C" void kernel_launch(void* const* d_in, const int* in_sizes, int n_in,
                              void* d_out, int out_size, void* d_ws, size_t ws_size,
                              hipStream_t stream)
{
    const float* x      = (const float*)d_in[0];
    const float* W_in   = (const float*)d_in[1];
    const float* conv_w = (const float*)d_in[2];
    const float* conv_b = (const float*)d_in[3];
    const float* ln_g   = (const float*)d_in[11];
    const float* ln_b   = (const float*)d_in[12];
    const float* W_out  = (const float*)d_in[13];
    float* out = (float*)d_out;

    // workspace layout (total ~108.2 MiB):
    //   Wc  : 192*192 f32          = 147456 B
    //   xf  : M*384 bf16           = 56623104 B   (reused for yln)
    //   xc  : M*384 bf16           = 56623104 B
    float* Wc = (float*)d_ws;
    unsigned short* xf = (unsigned short*)((char*)d_ws + 192*192*sizeof(float));
    unsigned short* xc = xf + (size_t)MTOT * DIV;

    wc_kernel      <<<dim3(192),           192, 0, stream>>>(W_out, W_in, Wc);
    gemm_in_kernel <<<dim3(MTOT/128, 3),   256, 0, stream>>>(x, W_in, xf);
    dwconv_kernel  <<<dim3(144, 6, B0V),   256, 0, stream>>>(xf, conv_w, conv_b, xc);
    boxln_kernel   <<<dim3(MTOT),          384, 0, stream>>>(xc, ln_g, ln_b, xf);
    gemm_out_kernel<<<dim3(MTOT/128, 3),   256, 0, stream>>>(xf, W_out, x, Wc, out);
}